// Round 4
// baseline (420.967 us; speedup 1.0000x reference)
//
#include <hip/hip_runtime.h>

// Problem constants (fixed by setup_inputs)
#define Bsz 512
#define Tsz 12
#define Dsz 1024
#define Osz 512

// Tile config: BM=96 (8 batches x 12 t), BN=128, BK=32, 256 threads.
// Thread tile 6m x 8n  (ty 0..15 -> 6 rows each; tx 0..15 -> 8 cols each).
// Grid = (512/128) x (512/8) = 4 x 64 = 256 blocks = exactly 1 per CU.
#define NBATCH 8
#define BM 96
#define BN 128
#define NTH 256

#define AS_BYTES (BM * 32 * 4)            // 12288
#define WS_BYTES (BN * 32 * 4)            // 16384
#define TILE_BYTES (AS_BYTES + WS_BYTES)  // 28672; x2 double-buffered = 57344

#define BUFST 136                          // lin reshuffle row stride (floats): <=2-way banks
// LDS layout (byte offsets):
//   GEMM:  tiles @0 .. 57344 (2 x (As,Ws)), XOR-swizzled k-granules
//   post:  buf   @0      (96*136*4 = 52224)   [lin reshuffle]
//          xs    @0      (12*1024*4 = 49152)  [fix-phase x rows, after buf dead]
//   always-safe high region:
//          list2d @57344 (8*128*4 = 4096)
//          cnt8   @61440 (32)
//          laL    @61472 (12*256*8 = 24576)
//          pidL   @86048 (256*4 = 1024)  -> total 87072
#define LIST_OFF 57344
#define CNT_OFF  61440
#define LAL_OFF  61472
#define PID_OFF  86048
#define SMEM_BYTES 87072

#define MARGIN 1e-3f   // worst-case fp32 lin error ~3.7e-4 (incl. 1.25x dyn gain); 2.7x headroom
#define MAXL 256       // deferred-dynamics capacity (flush when fill > 128)

__global__ __launch_bounds__(NTH, 1) void snn_fused(
    const float* __restrict__ x,      // (B, T, D)
    const float* __restrict__ Wm,     // (O, D)
    const float* __restrict__ bias,   // (O)
    float* __restrict__ out)          // (B, O)
{
    __shared__ __align__(16) char smem[SMEM_BYTES];
    float* bufp   = reinterpret_cast<float*>(smem);
    float* xs     = reinterpret_cast<float*>(smem);
    int*   list2d = reinterpret_cast<int*>(smem + LIST_OFF);
    int*   cnt8   = reinterpret_cast<int*>(smem + CNT_OFF);
    double* laL   = reinterpret_cast<double*>(smem + LAL_OFF);
    int*   pidL   = reinterpret_cast<int*>(smem + PID_OFF);

    const int tid = threadIdx.x;
    const int ty  = tid >> 4;    // 0..15 -> rows ty*6 .. ty*6+5
    const int tx  = tid & 15;    // 0..15 -> cols tx*8 .. tx*8+7

    const int n0 = blockIdx.x * BN;      // output-feature tile base
    const int b0 = blockIdx.y * NBATCH;  // batch tile base
    const int r0 = b0 * Tsz;             // first row of flattened A

    const float* Ab = x  + (size_t)r0 * Dsz;
    const float* Wb = Wm + (size_t)n0 * Dsz;

    // ---- per-thread staging descriptors (constant) ----
    // A: 768 quads (96 rows x 8), W: 1024 quads (128 x 8); 3 resp. 4 per thread.
    int gA[3], sA[3], gW[4], sW[4];
#pragma unroll
    for (int i = 0; i < 3; ++i) {
        int f = tid + NTH * i;
        int row = f >> 3, q = f & 7;
        gA[i] = row * Dsz + q * 4;
        sA[i] = row * 128 + ((q ^ ((row >> 3) & 7)) << 4);
    }
#pragma unroll
    for (int j = 0; j < 4; ++j) {
        int f = tid + NTH * j;
        int row = f >> 3, q = f & 7;
        gW[j] = row * Dsz + q * 4;
        sW[j] = row * 128 + ((q ^ ((row >> 3) & 7)) << 4);
    }

    // ---- compute-read constants ----
    int aBase[6], aG[6], wBase[8];
#pragma unroll
    for (int i = 0; i < 6; ++i) {
        int r = ty * 6 + i;
        aBase[i] = r * 128;
        aG[i]    = (r >> 3) & 7;
    }
#pragma unroll
    for (int j = 0; j < 8; ++j) wBase[j] = (tx * 8 + j) * 128;
    const int wG = tx & 7;

    float acc[6][8];
#pragma unroll
    for (int i = 0; i < 6; ++i)
#pragma unroll
        for (int j = 0; j < 8; ++j) acc[i][j] = 0.0f;

    // ---- prologue: stage k0=0 into buffer 0 ----
    {
        float4 ra[3], rw[4];
#pragma unroll
        for (int i = 0; i < 3; ++i) ra[i] = *reinterpret_cast<const float4*>(Ab + gA[i]);
#pragma unroll
        for (int j = 0; j < 4; ++j) rw[j] = *reinterpret_cast<const float4*>(Wb + gW[j]);
#pragma unroll
        for (int i = 0; i < 3; ++i) *reinterpret_cast<float4*>(smem + sA[i]) = ra[i];
#pragma unroll
        for (int j = 0; j < 4; ++j) *reinterpret_cast<float4*>(smem + AS_BYTES + sW[j]) = rw[j];
    }
    __syncthreads();

    // ---- main K loop: prefetch(k+1) -> compute(k) -> store(k+1) -> barrier ----
    int cur = 0;
    for (int k0i = 0; k0i < 32; ++k0i) {
        float4 ra[3], rw[4];
        const bool more = (k0i < 31);
        if (more) {
            const int k0n = (k0i + 1) * 32;
#pragma unroll
            for (int i = 0; i < 3; ++i) ra[i] = *reinterpret_cast<const float4*>(Ab + gA[i] + k0n);
#pragma unroll
            for (int j = 0; j < 4; ++j) rw[j] = *reinterpret_cast<const float4*>(Wb + gW[j] + k0n);
        }

        const char* As = smem + cur * TILE_BYTES;
        const char* Ws = As + AS_BYTES;
#pragma unroll
        for (int kq = 0; kq < 8; ++kq) {
            const int kow = ((kq ^ wG) << 4);
            float4 w4[8], a4[6];
#pragma unroll
            for (int j = 0; j < 8; ++j)
                w4[j] = *reinterpret_cast<const float4*>(Ws + wBase[j] + kow);
#pragma unroll
            for (int i = 0; i < 6; ++i)
                a4[i] = *reinterpret_cast<const float4*>(As + aBase[i] + ((kq ^ aG[i]) << 4));
#pragma unroll
            for (int i = 0; i < 6; ++i)
#pragma unroll
                for (int j = 0; j < 8; ++j) {
                    float t0 = fmaf(a4[i].x, w4[j].x, acc[i][j]);
                    t0 = fmaf(a4[i].y, w4[j].y, t0);
                    t0 = fmaf(a4[i].z, w4[j].z, t0);
                    acc[i][j] = fmaf(a4[i].w, w4[j].w, t0);
                }
        }

        if (more) {
            char* nt = smem + (cur ^ 1) * TILE_BYTES;
#pragma unroll
            for (int i = 0; i < 3; ++i) *reinterpret_cast<float4*>(nt + sA[i]) = ra[i];
#pragma unroll
            for (int j = 0; j < 4; ++j) *reinterpret_cast<float4*>(nt + AS_BYTES + sW[j]) = rw[j];
            __syncthreads();
            cur ^= 1;
        }
    }

    // ---- reshuffle lin into buf (overlaps tile buffers; all reads done) ----
    __syncthreads();
#pragma unroll
    for (int i = 0; i < 6; ++i) {
        const int row = ty * 6 + i;
        float4 o0, o1;
        o0.x = acc[i][0]; o0.y = acc[i][1]; o0.z = acc[i][2]; o0.w = acc[i][3];
        o1.x = acc[i][4]; o1.y = acc[i][5]; o1.z = acc[i][6]; o1.w = acc[i][7];
        *reinterpret_cast<float4*>(&bufp[row * BUFST + tx * 8])     = o0;
        *reinterpret_cast<float4*>(&bufp[row * BUFST + tx * 8 + 4]) = o1;
    }
    if (tid < 8) cnt8[tid] = 0;
    __syncthreads();

    // ---- main dynamics (fp32) + margin flagging ----
    for (int p = tid; p < NBATCH * BN; p += NTH) {
        const int bl = p >> 7;
        const int ol = p & 127;
        const float bv = bias[n0 + ol];
        float la[Tsz];
#pragma unroll
        for (int t = 0; t < Tsz; ++t)
            la[t] = bufp[(bl * Tsz + t) * BUFST + ol] + bv;

        float v = 0.0f, s = 0.0f, minm = 1e30f, cf = 0.0f;
        for (int oi = 0; oi < Tsz; ++oi) {
            float c = 0.0f;
#pragma unroll
            for (int t = 0; t < Tsz; ++t) {
                v = v * 0.2f * (1.0f - s) + la[t];
                minm = fminf(minm, fabsf(v - 0.5f));
                s = (v > 0.5f) ? 1.0f : 0.0f;
                c += s;
            }
            cf = c;
        }
        out[(size_t)(b0 + bl) * Osz + (n0 + ol)] = cf;
        if (minm < MARGIN) {
            int sl = atomicAdd(&cnt8[bl], 1);
            list2d[bl * 128 + sl] = ol;   // capacity 128 = pairs per bl, exact
        }
    }
    __syncthreads();

    // ---- exact fp64 recompute for flagged pairs (per-bl, x staged in LDS) ----
    const int g   = tid >> 4;   // 16-lane group 0..15
    const int l16 = tid & 15;
    int m = 0;                  // laL fill (uniform)

    for (int bl = 0; bl < NBATCH; ++bl) {
        const int n = cnt8[bl];
        if (n == 0) continue;
        // stage this batch's 12 x-rows (48 KB) into LDS (linear, coalesced)
        const float* xb = x + ((size_t)(b0 + bl) * Tsz) * Dsz;
        for (int i = tid; i < 3072; i += NTH)
            *reinterpret_cast<float4*>(xs + i * 4) = *reinterpret_cast<const float4*>(xb + i * 4);
        __syncthreads();

        for (int i = g; i < n; i += 16) {
            const int ol = list2d[bl * 128 + i];
            const float* wr = Wm + (size_t)(n0 + ol) * Dsz;
            double dot[Tsz];
#pragma unroll
            for (int t = 0; t < Tsz; ++t) dot[t] = 0.0;
            for (int c = 0; c < 16; ++c) {
                float4 w4 = *reinterpret_cast<const float4*>(wr + c * 64 + l16 * 4);
                const double w0 = (double)w4.x, w1 = (double)w4.y,
                             w2 = (double)w4.z, w3 = (double)w4.w;
#pragma unroll
                for (int t = 0; t < Tsz; ++t) {
                    float4 x4 = *reinterpret_cast<const float4*>(xs + t * 1024 + c * 64 + l16 * 4);
                    double d = dot[t];
                    d = fma((double)x4.x, w0, d);
                    d = fma((double)x4.y, w1, d);
                    d = fma((double)x4.z, w2, d);
                    dot[t] = fma((double)x4.w, w3, d);
                }
            }
#pragma unroll
            for (int off = 8; off; off >>= 1)
#pragma unroll
                for (int t = 0; t < Tsz; ++t)
                    dot[t] += __shfl_down(dot[t], off, 16);
            if (l16 == 0) {
                const double bv = (double)bias[n0 + ol];
#pragma unroll
                for (int t = 0; t < Tsz; ++t) laL[t * MAXL + (m + i)] = dot[t] + bv;
                pidL[m + i] = (bl << 7) | ol;
            }
        }
        m += n;
        __syncthreads();

        if (m > MAXL - 128) {   // flush deferred exact dynamics
            if (tid < m) {
                const int p = pidL[tid];
                const int fbl = p >> 7, fol = p & 127;
                double la[Tsz];
#pragma unroll
                for (int t = 0; t < Tsz; ++t) la[t] = laL[t * MAXL + tid];
                double v = 0.0, s = 0.0, c = 0.0;
                for (int oi = 0; oi < Tsz; ++oi) {
                    c = 0.0;
#pragma unroll
                    for (int t = 0; t < Tsz; ++t) {
                        v = v * 0.2 * (1.0 - s) + la[t];
                        s = (v > 0.5) ? 1.0 : 0.0;
                        c += s;
                    }
                }
                out[(size_t)(b0 + fbl) * Osz + (n0 + fol)] = (float)c;
            }
            __syncthreads();
            m = 0;
        }
    }
    if (m > 0 && tid < m) {
        const int p = pidL[tid];
        const int fbl = p >> 7, fol = p & 127;
        double la[Tsz];
#pragma unroll
        for (int t = 0; t < Tsz; ++t) la[t] = laL[t * MAXL + tid];
        double v = 0.0, s = 0.0, c = 0.0;
        for (int oi = 0; oi < Tsz; ++oi) {
            c = 0.0;
#pragma unroll
            for (int t = 0; t < Tsz; ++t) {
                v = v * 0.2 * (1.0 - s) + la[t];
                s = (v > 0.5) ? 1.0 : 0.0;
                c += s;
            }
        }
        out[(size_t)(b0 + fbl) * Osz + (n0 + fol)] = (float)c;
    }
}

extern "C" void kernel_launch(void* const* d_in, const int* in_sizes, int n_in,
                              void* d_out, int out_size, void* d_ws, size_t ws_size,
                              hipStream_t stream) {
    const float* x    = (const float*)d_in[0];   // (512,12,1024) fp32
    const float* Wm   = (const float*)d_in[1];   // (512,1024) fp32
    const float* bias = (const float*)d_in[2];   // (512) fp32
    float* out = (float*)d_out;                  // (512,512) fp32

    dim3 grid(Osz / BN, Bsz / NBATCH);   // (4, 64) = 256 blocks = 1/CU
    dim3 block(NTH);
    hipLaunchKernelGGL(snn_fused, grid, block, 0, stream, x, Wm, bias, out);
}

// Round 6
// 366.826 us; speedup vs baseline: 1.1476x; 1.1476x over previous
//
#include <hip/hip_runtime.h>

// Problem constants (fixed by setup_inputs)
#define Bsz 512
#define Tsz 12
#define Dsz 1024
#define Osz 512
#define Mrows (Bsz * Tsz)          // 6144 flattened rows
#define LIN_ELEMS (Mrows * Osz)    // 3145728
#define LIN_BYTES ((size_t)LIN_ELEMS * 4)

// ---------------- K1: SGEMM 6144x512x1024, 96x128 tiles, 6x8/thread ----------------
#define BM 96
#define BN 128
#define NTH1 256
#define AS_BYTES (BM * 32 * 4)             // 12288
#define WS_BYTES (BN * 32 * 4)             // 16384
#define TILE_BYTES (AS_BYTES + WS_BYTES)   // 28672; x2 dbuf = 57344

__global__ __launch_bounds__(NTH1) void gemm_tile(
    const float* __restrict__ x,     // (6144, 1024)
    const float* __restrict__ Wm,    // (512, 1024)
    float* __restrict__ lin,         // ws: (splitk, 6144, 512)
    int nk)                          // K-steps per split (32/splitk)
{
    __shared__ __align__(16) char smem[2 * TILE_BYTES];
    const int tid = threadIdx.x;
    const int ty  = tid >> 4;    // 0..15 -> rows ty*6 .. ty*6+5
    const int tx  = tid & 15;    // 0..15 -> cols tx*8 .. tx*8+7

    const int m0 = blockIdx.x * BM;
    const int n0 = blockIdx.y * BN;
    const int kbase = blockIdx.z * nk * 32;
    float* dst = lin + (size_t)blockIdx.z * LIN_ELEMS;

    const float* Ab = x  + (size_t)m0 * Dsz + kbase;
    const float* Wb = Wm + (size_t)n0 * Dsz + kbase;

    // staging descriptors: A 768 quads -> 3/thread; W 1024 quads -> 4/thread
    int gA[3], sA[3], gW[4], sW[4];
#pragma unroll
    for (int i = 0; i < 3; ++i) {
        int f = tid + NTH1 * i;
        int row = f >> 3, q = f & 7;
        gA[i] = row * Dsz + q * 4;
        sA[i] = row * 128 + ((q ^ ((row >> 3) & 7)) << 4);   // XOR-swizzled 16B granule
    }
#pragma unroll
    for (int j = 0; j < 4; ++j) {
        int f = tid + NTH1 * j;
        int row = f >> 3, q = f & 7;
        gW[j] = row * Dsz + q * 4;
        sW[j] = row * 128 + ((q ^ ((row >> 3) & 7)) << 4);
    }

    int aBase[6], aG[6], wBase[8];
#pragma unroll
    for (int i = 0; i < 6; ++i) {
        int r = ty * 6 + i;
        aBase[i] = r * 128;
        aG[i]    = (r >> 3) & 7;
    }
#pragma unroll
    for (int j = 0; j < 8; ++j) wBase[j] = (tx * 8 + j) * 128;
    const int wG = tx & 7;

    float acc[6][8];
#pragma unroll
    for (int i = 0; i < 6; ++i)
#pragma unroll
        for (int j = 0; j < 8; ++j) acc[i][j] = 0.0f;

    // prologue: stage step 0 into buffer 0
    {
        float4 ra[3], rw[4];
#pragma unroll
        for (int i = 0; i < 3; ++i) ra[i] = *reinterpret_cast<const float4*>(Ab + gA[i]);
#pragma unroll
        for (int j = 0; j < 4; ++j) rw[j] = *reinterpret_cast<const float4*>(Wb + gW[j]);
#pragma unroll
        for (int i = 0; i < 3; ++i) *reinterpret_cast<float4*>(smem + sA[i]) = ra[i];
#pragma unroll
        for (int j = 0; j < 4; ++j) *reinterpret_cast<float4*>(smem + AS_BYTES + sW[j]) = rw[j];
    }
    __syncthreads();

    int cur = 0;
    for (int k0i = 0; k0i < nk; ++k0i) {
        float4 ra[3], rw[4];
        const bool more = (k0i < nk - 1);
        if (more) {
            const int k0n = (k0i + 1) * 32;
#pragma unroll
            for (int i = 0; i < 3; ++i) ra[i] = *reinterpret_cast<const float4*>(Ab + gA[i] + k0n);
#pragma unroll
            for (int j = 0; j < 4; ++j) rw[j] = *reinterpret_cast<const float4*>(Wb + gW[j] + k0n);
        }

        const char* As = smem + cur * TILE_BYTES;
        const char* Ws = As + AS_BYTES;
#pragma unroll
        for (int kq = 0; kq < 8; ++kq) {
            const int kow = ((kq ^ wG) << 4);
            float4 w4[8];
#pragma unroll
            for (int j = 0; j < 8; ++j)
                w4[j] = *reinterpret_cast<const float4*>(Ws + wBase[j] + kow);
#pragma unroll
            for (int i = 0; i < 6; ++i) {
                float4 a4 = *reinterpret_cast<const float4*>(As + aBase[i] + ((kq ^ aG[i]) << 4));
#pragma unroll
                for (int j = 0; j < 8; ++j) {
                    float t0 = fmaf(a4.x, w4[j].x, acc[i][j]);
                    t0 = fmaf(a4.y, w4[j].y, t0);
                    t0 = fmaf(a4.z, w4[j].z, t0);
                    acc[i][j] = fmaf(a4.w, w4[j].w, t0);
                }
            }
        }

        if (more) {
            char* nt = smem + (cur ^ 1) * TILE_BYTES;
#pragma unroll
            for (int i = 0; i < 3; ++i) *reinterpret_cast<float4*>(nt + sA[i]) = ra[i];
#pragma unroll
            for (int j = 0; j < 4; ++j) *reinterpret_cast<float4*>(nt + AS_BYTES + sW[j]) = rw[j];
            __syncthreads();
            cur ^= 1;
        }
    }

    // epilogue: straight to global (no LDS reshuffle)
#pragma unroll
    for (int i = 0; i < 6; ++i) {
        const int row = m0 + ty * 6 + i;
        float4 o0, o1;
        o0.x = acc[i][0]; o0.y = acc[i][1]; o0.z = acc[i][2]; o0.w = acc[i][3];
        o1.x = acc[i][4]; o1.y = acc[i][5]; o1.z = acc[i][6]; o1.w = acc[i][7];
        float* p = dst + (size_t)row * Osz + n0 + tx * 8;
        *reinterpret_cast<float4*>(p)     = o0;
        *reinterpret_cast<float4*>(p + 4) = o1;
    }
}

// ---------------- K2: dynamics + margin flag + exact fp64 fix ----------------
// MARGIN: fp32 1024-term accum worst-case ~3.5e-5, x1.25 recurrence gain -> 4.4e-5 bound.
#define MARGIN 1e-4f

__global__ __launch_bounds__(256) void dyn_fix(
    const float* __restrict__ lin,   // ws: (nsplit, 6144, 512)
    int nsplit,
    const float* __restrict__ x,     // (512, 12, 1024)
    const float* __restrict__ Wm,    // (512, 1024)
    const float* __restrict__ bias,  // (512)
    float* __restrict__ out)         // (512, 512)
{
    __shared__ __align__(16) float xs[Tsz * Dsz];   // 48 KB: this batch's x rows
    __shared__ int list[Osz];
    __shared__ int cnt;

    const int b   = blockIdx.x;
    const int tid = threadIdx.x;
    if (tid == 0) cnt = 0;
    __syncthreads();

#pragma unroll
    for (int oo = 0; oo < 2; ++oo) {
        const int o = tid + oo * 256;
        const float bv = bias[o];
        float la[Tsz];
#pragma unroll
        for (int t = 0; t < Tsz; ++t) {
            const size_t idx = (size_t)(b * Tsz + t) * Osz + o;
            float v = lin[idx];
            if (nsplit == 2) v += lin[LIN_ELEMS + idx];
            la[t] = v + bv;
        }

        float v = 0.0f, s = 0.0f, minm = 1e30f, cf = 0.0f;
        for (int oi = 0; oi < Tsz; ++oi) {
            float c = 0.0f;
#pragma unroll
            for (int t = 0; t < Tsz; ++t) {
                v = v * 0.2f * (1.0f - s) + la[t];
                minm = fminf(minm, fabsf(v - 0.5f));
                s = (v > 0.5f) ? 1.0f : 0.0f;
                c += s;
            }
            cf = c;
        }
        out[(size_t)b * Osz + o] = cf;
        if (minm < MARGIN) {
            int sl = atomicAdd(&cnt, 1);
            list[sl] = o;
        }
    }
    __syncthreads();

    const int n = cnt;
    if (n == 0) return;

    // stage x[b] (12 x 1024) into LDS, coalesced
    const float* xb = x + (size_t)b * Tsz * Dsz;
    for (int i = tid; i < Tsz * Dsz / 4; i += 256)
        reinterpret_cast<float4*>(xs)[i] = reinterpret_cast<const float4*>(xb)[i];
    __syncthreads();

    // one wave per flagged pair: exact fp64 dot over k, then fp64 dynamics on lane 0
    const int wv = tid >> 6;
    const int l  = tid & 63;
    for (int fi = wv; fi < n; fi += 4) {
        const int o = list[fi];
        const float* wr = Wm + (size_t)o * Dsz + l * 16;
        double dot[Tsz];
#pragma unroll
        for (int t = 0; t < Tsz; ++t) dot[t] = 0.0;
#pragma unroll
        for (int c4 = 0; c4 < 4; ++c4) {
            float4 w4 = *reinterpret_cast<const float4*>(wr + c4 * 4);
            const double w0 = (double)w4.x, w1 = (double)w4.y,
                         w2 = (double)w4.z, w3 = (double)w4.w;
#pragma unroll
            for (int t = 0; t < Tsz; ++t) {
                float4 x4 = *reinterpret_cast<const float4*>(xs + t * Dsz + l * 16 + c4 * 4);
                double d = dot[t];
                d = fma((double)x4.x, w0, d);
                d = fma((double)x4.y, w1, d);
                d = fma((double)x4.z, w2, d);
                dot[t] = fma((double)x4.w, w3, d);
            }
        }
#pragma unroll
        for (int off = 32; off; off >>= 1)
#pragma unroll
            for (int t = 0; t < Tsz; ++t)
                dot[t] += __shfl_down(dot[t], off);
        if (l == 0) {
            const double bv = (double)bias[o];
            double v = 0.0, s = 0.0, c = 0.0;
            for (int oi = 0; oi < Tsz; ++oi) {
                c = 0.0;
#pragma unroll
                for (int t = 0; t < Tsz; ++t) {
                    v = v * 0.2 * (1.0 - s) + (dot[t] + bv);
                    s = (v > 0.5) ? 1.0 : 0.0;
                    c += s;
                }
            }
            out[(size_t)b * Osz + o] = (float)c;
        }
    }
}

// ---------------- Fallback: proven round-1 fused fp64 kernel (ws too small) ----------------
#define F_AST 100
#define F_WST 68
#define F_BUFST 65
#define F_ABYTES (32 * F_AST * 4)

__global__ __launch_bounds__(192) void snn_fused_fb(
    const float* __restrict__ x, const float* __restrict__ Wm,
    const float* __restrict__ bias, float* __restrict__ out)
{
    __shared__ __align__(16) char smem[96 * F_BUFST * 8];
    float*  AsT = reinterpret_cast<float*>(smem);
    float*  WsT = reinterpret_cast<float*>(smem + F_ABYTES);
    double* buf = reinterpret_cast<double*>(smem);

    const int tid = threadIdx.x;
    const int ty  = tid >> 4;
    const int tx  = tid & 15;
    const int n0 = blockIdx.x * 64;
    const int b0 = blockIdx.y * 8;
    const int r0 = b0 * Tsz;

    double acc[8][4];
#pragma unroll
    for (int i = 0; i < 8; ++i)
#pragma unroll
        for (int j = 0; j < 4; ++j) acc[i][j] = 0.0;

    const float* Abase = x  + (size_t)r0 * Dsz;
    const float* Wbase = Wm + (size_t)n0 * Dsz;

    for (int k0 = 0; k0 < Dsz; k0 += 32) {
        __syncthreads();
#pragma unroll
        for (int it = 0; it < 4; ++it) {
            int idx = tid + 192 * it;
            int row = idx >> 3, c4 = idx & 7;
            float4 v = *reinterpret_cast<const float4*>(Abase + (size_t)row * Dsz + k0 + c4 * 4);
            int kb = c4 * 4;
            AsT[(kb + 0) * F_AST + row] = v.x;
            AsT[(kb + 1) * F_AST + row] = v.y;
            AsT[(kb + 2) * F_AST + row] = v.z;
            AsT[(kb + 3) * F_AST + row] = v.w;
        }
#pragma unroll
        for (int it = 0; it < 3; ++it) {
            int idx = tid + 192 * it;
            if (idx < 512) {
                int row = idx >> 3, c4 = idx & 7;
                float4 v = *reinterpret_cast<const float4*>(Wbase + (size_t)row * Dsz + k0 + c4 * 4);
                int kb = c4 * 4;
                WsT[(kb + 0) * F_WST + row] = v.x;
                WsT[(kb + 1) * F_WST + row] = v.y;
                WsT[(kb + 2) * F_WST + row] = v.z;
                WsT[(kb + 3) * F_WST + row] = v.w;
            }
        }
        __syncthreads();
#pragma unroll 4
        for (int kk = 0; kk < 32; ++kk) {
            const float* ar = &AsT[kk * F_AST + ty * 8];
            float4 a0 = *reinterpret_cast<const float4*>(ar);
            float4 a1 = *reinterpret_cast<const float4*>(ar + 4);
            float4 w0 = *reinterpret_cast<const float4*>(&WsT[kk * F_WST + tx * 4]);
            double ad[8] = {(double)a0.x, (double)a0.y, (double)a0.z, (double)a0.w,
                            (double)a1.x, (double)a1.y, (double)a1.z, (double)a1.w};
            double wd[4] = {(double)w0.x, (double)w0.y, (double)w0.z, (double)w0.w};
#pragma unroll
            for (int i = 0; i < 8; ++i)
#pragma unroll
                for (int j = 0; j < 4; ++j)
                    acc[i][j] = fma(ad[i], wd[j], acc[i][j]);
        }
    }
    __syncthreads();
#pragma unroll
    for (int i = 0; i < 8; ++i)
#pragma unroll
        for (int j = 0; j < 4; ++j)
            buf[(ty * 8 + i) * F_BUFST + (tx * 4 + j)] = acc[i][j];
    __syncthreads();

    for (int idx = tid; idx < 512; idx += 192) {
        int bl = idx >> 6, ol = idx & 63;
        double bv = (double)bias[n0 + ol];
        double la[Tsz];
#pragma unroll
        for (int t = 0; t < Tsz; ++t)
            la[t] = buf[(bl * Tsz + t) * F_BUFST + ol] + bv;
        double v = 0.0, s = 0.0;
        float cnt = 0.0f;
        for (int oi = 0; oi < Tsz; ++oi) {
            double c = 0.0;
#pragma unroll
            for (int t = 0; t < Tsz; ++t) {
                v = v * 0.2 * (1.0 - s) + la[t];
                s = (v > 0.5) ? 1.0 : 0.0;
                c += s;
            }
            cnt = (float)c;
        }
        out[(size_t)(b0 + bl) * Osz + (n0 + ol)] = cnt;
    }
}

extern "C" void kernel_launch(void* const* d_in, const int* in_sizes, int n_in,
                              void* d_out, int out_size, void* d_ws, size_t ws_size,
                              hipStream_t stream) {
    const float* x    = (const float*)d_in[0];   // (512,12,1024) fp32
    const float* Wm   = (const float*)d_in[1];   // (512,1024) fp32
    const float* bias = (const float*)d_in[2];   // (512) fp32
    float* out = (float*)d_out;                  // (512,512) fp32

    if (ws_size >= LIN_BYTES) {
        const int splitk = (ws_size >= 2 * LIN_BYTES) ? 2 : 1;
        float* lin = (float*)d_ws;
        dim3 g1(Mrows / BM, Osz / BN, splitk);   // (64, 4, splitk)
        hipLaunchKernelGGL(gemm_tile, g1, dim3(NTH1), 0, stream, x, Wm, lin, 32 / splitk);
        hipLaunchKernelGGL(dyn_fix, dim3(Bsz), dim3(256), 0, stream,
                           lin, splitk, x, Wm, bias, out);
    } else {
        dim3 grid(Osz / 64, Bsz / 8);            // (8, 64)
        hipLaunchKernelGGL(snn_fused_fb, grid, dim3(192), 0, stream, x, Wm, bias, out);
    }
}

// Round 7
// 215.810 us; speedup vs baseline: 1.9506x; 1.6998x over previous
//
#include <hip/hip_runtime.h>

// Problem constants (fixed by setup_inputs)
#define Bsz 512
#define Tsz 12
#define Dsz 1024
#define Osz 512
#define Mrows (Bsz * Tsz)          // 6144 flattened rows
#define LIN_ELEMS (Mrows * Osz)    // 3145728
#define LIN_BYTES ((size_t)LIN_ELEMS * 4)

// ---------------- K1: SGEMM 6144x512x1024, 128x128 tile, 8x8/thread ----------------
// LDS layout: k-major transposed tiles, IMMEDIATE-OFFSET reads (no runtime XOR:
// that was R4-R6's 256-VGPR spill cause). AST=WST=132 floats (132 mod 32 = 4).
#define BM 128
#define BN 128
#define NTH1 256
#define AST 132
#define TILE_FLOATS (2 * 32 * AST)          // As + Ws per buffer = 8448 floats
#define TILE_BYTES  (TILE_FLOATS * 4)       // 33792; x2 dbuf = 67584

__global__ __launch_bounds__(NTH1) void gemm_tile(
    const float* __restrict__ x,     // (6144, 1024)
    const float* __restrict__ Wm,    // (512, 1024)
    float* __restrict__ lin,         // ws: (splitk, 6144, 512)
    int nk)                          // K-steps (of 32) per split
{
    __shared__ __align__(16) float smem[2 * TILE_FLOATS];
    const int tid = threadIdx.x;
    const int ty  = tid >> 4;    // 0..15 -> rows ty*8 .. ty*8+7
    const int tx  = tid & 15;    // 0..15 -> cols {tx*4..+3} and {64+tx*4..+3}

    const int m0 = blockIdx.x * BM;
    const int n0 = blockIdx.y * BN;
    const int kbase = blockIdx.z * nk * 32;
    float* dst = lin + (size_t)blockIdx.z * LIN_ELEMS;

    const float* Ab = x  + (size_t)m0 * Dsz + kbase;
    const float* Wb = Wm + (size_t)n0 * Dsz + kbase;

    // staging descriptors: 1024 quads each for A and W -> 4 per thread each.
    // global: row*Dsz + c4*4 ; LDS store base (floats): (c4*4)*AST + row, +AST per j.
    int gS[4], sS[4];
#pragma unroll
    for (int i = 0; i < 4; ++i) {
        int f = tid + NTH1 * i;
        int row = f >> 3, c4 = f & 7;
        gS[i] = row * Dsz + c4 * 4;
        sS[i] = (c4 * 4) * AST + row;
    }

    float acc[8][8];
#pragma unroll
    for (int i = 0; i < 8; ++i)
#pragma unroll
        for (int j = 0; j < 8; ++j) acc[i][j] = 0.0f;

    // prologue: stage K-step 0 into buffer 0
    {
        float4 ra[4], rw[4];
#pragma unroll
        for (int i = 0; i < 4; ++i) ra[i] = *reinterpret_cast<const float4*>(Ab + gS[i]);
#pragma unroll
        for (int i = 0; i < 4; ++i) rw[i] = *reinterpret_cast<const float4*>(Wb + gS[i]);
#pragma unroll
        for (int i = 0; i < 4; ++i) {
            float* pa = smem + sS[i];
            pa[0] = ra[i].x; pa[AST] = ra[i].y; pa[2 * AST] = ra[i].z; pa[3 * AST] = ra[i].w;
            float* pw = smem + 32 * AST + sS[i];
            pw[0] = rw[i].x; pw[AST] = rw[i].y; pw[2 * AST] = rw[i].z; pw[3 * AST] = rw[i].w;
        }
    }
    __syncthreads();

    int cur = 0;
    for (int k0i = 0; k0i < nk; ++k0i) {
        float4 ra[4], rw[4];
        const bool more = (k0i < nk - 1);
        if (more) {
            const int k0n = (k0i + 1) * 32;
#pragma unroll
            for (int i = 0; i < 4; ++i) ra[i] = *reinterpret_cast<const float4*>(Ab + gS[i] + k0n);
#pragma unroll
            for (int i = 0; i < 4; ++i) rw[i] = *reinterpret_cast<const float4*>(Wb + gS[i] + k0n);
        }

        // compute on buffer cur: all LDS reads are base + compile-time immediate
        const float* As = smem + cur * TILE_FLOATS + ty * 8;          // A base (row ty*8)
        const float* Ws = smem + cur * TILE_FLOATS + 32 * AST + tx * 4; // W base (col tx*4)
#pragma unroll 8
        for (int kk = 0; kk < 32; ++kk) {
            float4 a0 = *reinterpret_cast<const float4*>(As + kk * AST);
            float4 a1 = *reinterpret_cast<const float4*>(As + kk * AST + 4);
            float4 w0 = *reinterpret_cast<const float4*>(Ws + kk * AST);
            float4 w1 = *reinterpret_cast<const float4*>(Ws + kk * AST + 64);
            float av[8] = {a0.x, a0.y, a0.z, a0.w, a1.x, a1.y, a1.z, a1.w};
            float wv[8] = {w0.x, w0.y, w0.z, w0.w, w1.x, w1.y, w1.z, w1.w};
#pragma unroll
            for (int i = 0; i < 8; ++i)
#pragma unroll
                for (int j = 0; j < 8; ++j)
                    acc[i][j] = fmaf(av[i], wv[j], acc[i][j]);
        }

        if (more) {
            float* nt = smem + (cur ^ 1) * TILE_FLOATS;
#pragma unroll
            for (int i = 0; i < 4; ++i) {
                float* pa = nt + sS[i];
                pa[0] = ra[i].x; pa[AST] = ra[i].y; pa[2 * AST] = ra[i].z; pa[3 * AST] = ra[i].w;
                float* pw = nt + 32 * AST + sS[i];
                pw[0] = rw[i].x; pw[AST] = rw[i].y; pw[2 * AST] = rw[i].z; pw[3 * AST] = rw[i].w;
            }
            __syncthreads();
            cur ^= 1;
        }
    }

    // epilogue: straight to global, two float4 column blocks per row
#pragma unroll
    for (int i = 0; i < 8; ++i) {
        const int row = m0 + ty * 8 + i;
        float4 o0, o1;
        o0.x = acc[i][0]; o0.y = acc[i][1]; o0.z = acc[i][2]; o0.w = acc[i][3];
        o1.x = acc[i][4]; o1.y = acc[i][5]; o1.z = acc[i][6]; o1.w = acc[i][7];
        float* p = dst + (size_t)row * Osz + n0;
        *reinterpret_cast<float4*>(p + tx * 4)      = o0;
        *reinterpret_cast<float4*>(p + 64 + tx * 4) = o1;
    }
}

// ---------------- K2: dynamics + margin flag + exact fp64 fix ----------------
// MARGIN: realistic fp32 lin error ~3e-6 (incl. recurrence gain 1.25x); 30x headroom.
#define MARGIN 1e-4f

__global__ __launch_bounds__(256) void dyn_fix(
    const float* __restrict__ lin,   // ws: (nsplit, 6144, 512)
    int nsplit,
    const float* __restrict__ x,     // (512, 12, 1024)
    const float* __restrict__ Wm,    // (512, 1024)
    const float* __restrict__ bias,  // (512)
    float* __restrict__ out)         // (512, 512)
{
    __shared__ __align__(16) float xs[Tsz * Dsz];   // 48 KB: this batch's x rows
    __shared__ int list[Osz];
    __shared__ int cnt;

    const int b   = blockIdx.x;
    const int tid = threadIdx.x;
    if (tid == 0) cnt = 0;
    __syncthreads();

#pragma unroll
    for (int oo = 0; oo < 2; ++oo) {
        const int o = tid + oo * 256;
        const float bv = bias[o];
        float la[Tsz];
#pragma unroll
        for (int t = 0; t < Tsz; ++t) {
            const size_t idx = (size_t)(b * Tsz + t) * Osz + o;
            float v = lin[idx];
            for (int s = 1; s < nsplit; ++s) v += lin[(size_t)s * LIN_ELEMS + idx];
            la[t] = v + bv;
        }

        float v = 0.0f, s = 0.0f, minm = 1e30f, cf = 0.0f;
        for (int oi = 0; oi < Tsz; ++oi) {
            float c = 0.0f;
#pragma unroll
            for (int t = 0; t < Tsz; ++t) {
                v = v * 0.2f * (1.0f - s) + la[t];
                minm = fminf(minm, fabsf(v - 0.5f));
                s = (v > 0.5f) ? 1.0f : 0.0f;
                c += s;
            }
            cf = c;
        }
        out[(size_t)b * Osz + o] = cf;
        if (minm < MARGIN) {
            int sl = atomicAdd(&cnt, 1);
            list[sl] = o;
        }
    }
    __syncthreads();

    const int n = cnt;
    if (n == 0) return;

    // stage x[b] (12 x 1024) into LDS, coalesced
    const float* xb = x + (size_t)b * Tsz * Dsz;
    for (int i = tid; i < Tsz * Dsz / 4; i += 256)
        reinterpret_cast<float4*>(xs)[i] = reinterpret_cast<const float4*>(xb)[i];
    __syncthreads();

    // one wave per flagged pair: exact fp64 dot over k, then fp64 dynamics on lane 0
    const int wv = tid >> 6;
    const int l  = tid & 63;
    for (int fi = wv; fi < n; fi += 4) {
        const int o = list[fi];
        const float* wr = Wm + (size_t)o * Dsz + l * 16;
        double dot[Tsz];
#pragma unroll
        for (int t = 0; t < Tsz; ++t) dot[t] = 0.0;
#pragma unroll
        for (int c4 = 0; c4 < 4; ++c4) {
            float4 w4 = *reinterpret_cast<const float4*>(wr + c4 * 4);
            const double w0 = (double)w4.x, w1 = (double)w4.y,
                         w2 = (double)w4.z, w3 = (double)w4.w;
#pragma unroll
            for (int t = 0; t < Tsz; ++t) {
                float4 x4 = *reinterpret_cast<const float4*>(xs + t * Dsz + l * 16 + c4 * 4);
                double d = dot[t];
                d = fma((double)x4.x, w0, d);
                d = fma((double)x4.y, w1, d);
                d = fma((double)x4.z, w2, d);
                dot[t] = fma((double)x4.w, w3, d);
            }
        }
#pragma unroll
        for (int off = 32; off; off >>= 1)
#pragma unroll
            for (int t = 0; t < Tsz; ++t)
                dot[t] += __shfl_down(dot[t], off);
        if (l == 0) {
            const double bv = (double)bias[o];
            double v = 0.0, s = 0.0, c = 0.0;
            for (int oi = 0; oi < Tsz; ++oi) {
                c = 0.0;
#pragma unroll
                for (int t = 0; t < Tsz; ++t) {
                    v = v * 0.2 * (1.0 - s) + (dot[t] + bv);
                    s = (v > 0.5) ? 1.0 : 0.0;
                    c += s;
                }
            }
            out[(size_t)b * Osz + o] = (float)c;
        }
    }
}

// ---------------- Fallback: proven round-1 fused fp64 kernel (ws too small) ----------------
#define F_AST 100
#define F_WST 68
#define F_BUFST 65
#define F_ABYTES (32 * F_AST * 4)

__global__ __launch_bounds__(192) void snn_fused_fb(
    const float* __restrict__ x, const float* __restrict__ Wm,
    const float* __restrict__ bias, float* __restrict__ out)
{
    __shared__ __align__(16) char smem[96 * F_BUFST * 8];
    float*  AsT = reinterpret_cast<float*>(smem);
    float*  WsT = reinterpret_cast<float*>(smem + F_ABYTES);
    double* buf = reinterpret_cast<double*>(smem);

    const int tid = threadIdx.x;
    const int ty  = tid >> 4;
    const int tx  = tid & 15;
    const int n0 = blockIdx.x * 64;
    const int b0 = blockIdx.y * 8;
    const int r0 = b0 * Tsz;

    double acc[8][4];
#pragma unroll
    for (int i = 0; i < 8; ++i)
#pragma unroll
        for (int j = 0; j < 4; ++j) acc[i][j] = 0.0;

    const float* Abase = x  + (size_t)r0 * Dsz;
    const float* Wbase = Wm + (size_t)n0 * Dsz;

    for (int k0 = 0; k0 < Dsz; k0 += 32) {
        __syncthreads();
#pragma unroll
        for (int it = 0; it < 4; ++it) {
            int idx = tid + 192 * it;
            int row = idx >> 3, c4 = idx & 7;
            float4 v = *reinterpret_cast<const float4*>(Abase + (size_t)row * Dsz + k0 + c4 * 4);
            int kb = c4 * 4;
            AsT[(kb + 0) * F_AST + row] = v.x;
            AsT[(kb + 1) * F_AST + row] = v.y;
            AsT[(kb + 2) * F_AST + row] = v.z;
            AsT[(kb + 3) * F_AST + row] = v.w;
        }
#pragma unroll
        for (int it = 0; it < 3; ++it) {
            int idx = tid + 192 * it;
            if (idx < 512) {
                int row = idx >> 3, c4 = idx & 7;
                float4 v = *reinterpret_cast<const float4*>(Wbase + (size_t)row * Dsz + k0 + c4 * 4);
                int kb = c4 * 4;
                WsT[(kb + 0) * F_WST + row] = v.x;
                WsT[(kb + 1) * F_WST + row] = v.y;
                WsT[(kb + 2) * F_WST + row] = v.z;
                WsT[(kb + 3) * F_WST + row] = v.w;
            }
        }
        __syncthreads();
#pragma unroll 4
        for (int kk = 0; kk < 32; ++kk) {
            const float* ar = &AsT[kk * F_AST + ty * 8];
            float4 a0 = *reinterpret_cast<const float4*>(ar);
            float4 a1 = *reinterpret_cast<const float4*>(ar + 4);
            float4 w0 = *reinterpret_cast<const float4*>(&WsT[kk * F_WST + tx * 4]);
            double ad[8] = {(double)a0.x, (double)a0.y, (double)a0.z, (double)a0.w,
                            (double)a1.x, (double)a1.y, (double)a1.z, (double)a1.w};
            double wd[4] = {(double)w0.x, (double)w0.y, (double)w0.z, (double)w0.w};
#pragma unroll
            for (int i = 0; i < 8; ++i)
#pragma unroll
                for (int j = 0; j < 4; ++j)
                    acc[i][j] = fma(ad[i], wd[j], acc[i][j]);
        }
    }
    __syncthreads();
#pragma unroll
    for (int i = 0; i < 8; ++i)
#pragma unroll
        for (int j = 0; j < 4; ++j)
            buf[(ty * 8 + i) * F_BUFST + (tx * 4 + j)] = acc[i][j];
    __syncthreads();

    for (int idx = tid; idx < 512; idx += 192) {
        int bl = idx >> 6, ol = idx & 63;
        double bv = (double)bias[n0 + ol];
        double la[Tsz];
#pragma unroll
        for (int t = 0; t < Tsz; ++t)
            la[t] = buf[(bl * Tsz + t) * F_BUFST + ol] + bv;
        double v = 0.0, s = 0.0;
        float cnt = 0.0f;
        for (int oi = 0; oi < Tsz; ++oi) {
            double c = 0.0;
#pragma unroll
            for (int t = 0; t < Tsz; ++t) {
                v = v * 0.2 * (1.0 - s) + la[t];
                s = (v > 0.5) ? 1.0 : 0.0;
                c += s;
            }
            cnt = (float)c;
        }
        out[(size_t)(b0 + bl) * Osz + (n0 + ol)] = cnt;
    }
}

extern "C" void kernel_launch(void* const* d_in, const int* in_sizes, int n_in,
                              void* d_out, int out_size, void* d_ws, size_t ws_size,
                              hipStream_t stream) {
    const float* x    = (const float*)d_in[0];   // (512,12,1024) fp32
    const float* Wm   = (const float*)d_in[1];   // (512,1024) fp32
    const float* bias = (const float*)d_in[2];   // (512) fp32
    float* out = (float*)d_out;                  // (512,512) fp32

    if (ws_size >= LIN_BYTES) {
        int splitk = 1;
        if (ws_size >= 4 * LIN_BYTES) splitk = 4;
        else if (ws_size >= 2 * LIN_BYTES) splitk = 2;
        float* lin = (float*)d_ws;
        dim3 g1(Mrows / BM, Osz / BN, splitk);   // (48, 4, splitk)
        hipLaunchKernelGGL(gemm_tile, g1, dim3(NTH1), 0, stream, x, Wm, lin, 32 / splitk);
        hipLaunchKernelGGL(dyn_fix, dim3(Bsz), dim3(256), 0, stream,
                           lin, splitk, x, Wm, bias, out);
    } else {
        dim3 grid(Osz / 64, Bsz / 8);            // (8, 64)
        hipLaunchKernelGGL(snn_fused_fb, grid, dim3(192), 0, stream, x, Wm, bias, out);
    }
}

// Round 8
// 181.389 us; speedup vs baseline: 2.3208x; 1.1898x over previous
//
#include <hip/hip_runtime.h>

// Problem constants (fixed by setup_inputs)
#define Bsz 512
#define Tsz 12
#define Dsz 1024
#define Osz 512
#define Mrows (Bsz * Tsz)          // 6144 flattened rows
#define LIN_ELEMS (Mrows * Osz)    // 3145728
#define LIN_BYTES ((size_t)LIN_ELEMS * 4)

// ---------------- K1: SGEMM 6144x512x1024, 96x128 tile, 6x8/thread ----------------
// Grid = (6144/96) x (512/128) x splitk = 64 x 4 x 2 = 512 blocks = EXACTLY 2/CU:
// no tail generation (R7's 768-block grid ran 1.5 generations at 2/CU residency).
// k-major LDS tiles with IMMEDIATE-offset reads (R7-proven: no runtime XOR).
#define BM 96
#define BN 128
#define NTH1 256
#define ASTA 100                             // A tile row stride (mod 32 = 4)
#define ASTW 132                             // W tile row stride (mod 32 = 4)
#define A_FLOATS (32 * ASTA)                 // 3200
#define TILE_FLOATS (32 * ASTA + 32 * ASTW)  // 7424 floats = 29696 B; x2 dbuf = 59392 B

__global__ __launch_bounds__(NTH1) void gemm_tile(
    const float* __restrict__ x,     // (6144, 1024)
    const float* __restrict__ Wm,    // (512, 1024)
    float* __restrict__ lin,         // ws: (splitk, 6144, 512)
    int nk)                          // K-steps (of 32) per split
{
    __shared__ __align__(16) float smem[2 * TILE_FLOATS];
    const int tid = threadIdx.x;
    const int ty  = tid >> 4;    // 0..15 -> rows ty*6 .. ty*6+5
    const int tx  = tid & 15;    // 0..15 -> cols {tx*4..+3} and {64+tx*4..+3}

    const int m0 = blockIdx.x * BM;
    const int n0 = blockIdx.y * BN;
    const int kbase = blockIdx.z * nk * 32;
    float* dst = lin + (size_t)blockIdx.z * LIN_ELEMS;

    const float* Ab = x  + (size_t)m0 * Dsz + kbase;
    const float* Wb = Wm + (size_t)n0 * Dsz + kbase;

    // staging: A 96x8=768 quads -> 3/thread; W 128x8=1024 quads -> 4/thread
    int gA[3], sA[3], gW[4], sW[4];
#pragma unroll
    for (int i = 0; i < 3; ++i) {
        int f = tid + NTH1 * i;
        int row = f >> 3, c4 = f & 7;
        gA[i] = row * Dsz + c4 * 4;
        sA[i] = (c4 * 4) * ASTA + row;       // k-major: AsT[k][row]
    }
#pragma unroll
    for (int i = 0; i < 4; ++i) {
        int f = tid + NTH1 * i;
        int row = f >> 3, c4 = f & 7;
        gW[i] = row * Dsz + c4 * 4;
        sW[i] = (c4 * 4) * ASTW + row;       // k-major: WsT[k][col]
    }

    float acc[6][8];
#pragma unroll
    for (int i = 0; i < 6; ++i)
#pragma unroll
        for (int j = 0; j < 8; ++j) acc[i][j] = 0.0f;

    // prologue: stage K-step 0 into buffer 0
    {
        float4 ra[3], rw[4];
#pragma unroll
        for (int i = 0; i < 3; ++i) ra[i] = *reinterpret_cast<const float4*>(Ab + gA[i]);
#pragma unroll
        for (int i = 0; i < 4; ++i) rw[i] = *reinterpret_cast<const float4*>(Wb + gW[i]);
#pragma unroll
        for (int i = 0; i < 3; ++i) {
            float* pa = smem + sA[i];
            pa[0] = ra[i].x; pa[ASTA] = ra[i].y; pa[2 * ASTA] = ra[i].z; pa[3 * ASTA] = ra[i].w;
        }
#pragma unroll
        for (int i = 0; i < 4; ++i) {
            float* pw = smem + A_FLOATS + sW[i];
            pw[0] = rw[i].x; pw[ASTW] = rw[i].y; pw[2 * ASTW] = rw[i].z; pw[3 * ASTW] = rw[i].w;
        }
    }
    __syncthreads();

    int cur = 0;
    for (int k0i = 0; k0i < nk; ++k0i) {
        float4 ra[3], rw[4];
        const bool more = (k0i < nk - 1);
        if (more) {
            const int k0n = (k0i + 1) * 32;
#pragma unroll
            for (int i = 0; i < 3; ++i) ra[i] = *reinterpret_cast<const float4*>(Ab + gA[i] + k0n);
#pragma unroll
            for (int i = 0; i < 4; ++i) rw[i] = *reinterpret_cast<const float4*>(Wb + gW[i] + k0n);
        }

        // compute on buffer cur: all LDS reads base + compile-time immediate
        const float* As = smem + cur * TILE_FLOATS + ty * 6;             // 8B-aligned
        const float* Ws = smem + cur * TILE_FLOATS + A_FLOATS + tx * 4;
#pragma unroll 8
        for (int kk = 0; kk < 32; ++kk) {
            float2 a0 = *reinterpret_cast<const float2*>(As + kk * ASTA);
            float2 a1 = *reinterpret_cast<const float2*>(As + kk * ASTA + 2);
            float2 a2 = *reinterpret_cast<const float2*>(As + kk * ASTA + 4);
            float4 w0 = *reinterpret_cast<const float4*>(Ws + kk * ASTW);
            float4 w1 = *reinterpret_cast<const float4*>(Ws + kk * ASTW + 64);
            float av[6] = {a0.x, a0.y, a1.x, a1.y, a2.x, a2.y};
            float wv[8] = {w0.x, w0.y, w0.z, w0.w, w1.x, w1.y, w1.z, w1.w};
#pragma unroll
            for (int i = 0; i < 6; ++i)
#pragma unroll
                for (int j = 0; j < 8; ++j)
                    acc[i][j] = fmaf(av[i], wv[j], acc[i][j]);
        }

        if (more) {
            float* nt = smem + (cur ^ 1) * TILE_FLOATS;
#pragma unroll
            for (int i = 0; i < 3; ++i) {
                float* pa = nt + sA[i];
                pa[0] = ra[i].x; pa[ASTA] = ra[i].y; pa[2 * ASTA] = ra[i].z; pa[3 * ASTA] = ra[i].w;
            }
#pragma unroll
            for (int i = 0; i < 4; ++i) {
                float* pw = nt + A_FLOATS + sW[i];
                pw[0] = rw[i].x; pw[ASTW] = rw[i].y; pw[2 * ASTW] = rw[i].z; pw[3 * ASTW] = rw[i].w;
            }
            __syncthreads();
            cur ^= 1;
        }
    }

    // epilogue: straight to global
#pragma unroll
    for (int i = 0; i < 6; ++i) {
        const int row = m0 + ty * 6 + i;
        float4 o0, o1;
        o0.x = acc[i][0]; o0.y = acc[i][1]; o0.z = acc[i][2]; o0.w = acc[i][3];
        o1.x = acc[i][4]; o1.y = acc[i][5]; o1.z = acc[i][6]; o1.w = acc[i][7];
        float* p = dst + (size_t)row * Osz + n0;
        *reinterpret_cast<float4*>(p + tx * 4)      = o0;
        *reinterpret_cast<float4*>(p + 64 + tx * 4) = o1;
    }
}

// ---------------- K2: dynamics + margin flag + exact fp64 fix ----------------
// MARGIN: realistic fp32 lin error ~3e-6 (incl. 1.25x recurrence gain); 30x headroom.
// R7 lesson: load ALL split partials as independent vector loads FIRST (no dependent
// scalar-load+add chain), then sum — the chain was ~85 us of exposed HBM latency.
#define MARGIN 1e-4f

template <int NSPLIT>
__global__ __launch_bounds__(256) void dyn_fix(
    const float* __restrict__ lin,   // ws: (NSPLIT, 6144, 512)
    const float* __restrict__ x,     // (512, 12, 1024)
    const float* __restrict__ Wm,    // (512, 1024)
    const float* __restrict__ bias,  // (512)
    float* __restrict__ out)         // (512, 512)
{
    __shared__ __align__(16) float xs[Tsz * Dsz];   // 48 KB: this batch's x rows
    __shared__ int list[Osz];
    __shared__ int cnt;

    const int b   = blockIdx.x;
    const int tid = threadIdx.x;
    if (tid == 0) cnt = 0;
    __syncthreads();

    const int o = tid * 2;   // this thread owns outputs o, o+1
    {
        // gather all partials: 12*NSPLIT independent float2 loads, fully unrolled
        float2 part[Tsz][NSPLIT];
#pragma unroll
        for (int t = 0; t < Tsz; ++t)
#pragma unroll
            for (int s = 0; s < NSPLIT; ++s)
                part[t][s] = *reinterpret_cast<const float2*>(
                    lin + (size_t)s * LIN_ELEMS + (size_t)(b * Tsz + t) * Osz + o);

        const float2 bv = *reinterpret_cast<const float2*>(bias + o);
        float lax[Tsz], lay[Tsz];
#pragma unroll
        for (int t = 0; t < Tsz; ++t) {
            float sx = bv.x, sy = bv.y;
#pragma unroll
            for (int s = 0; s < NSPLIT; ++s) { sx += part[t][s].x; sy += part[t][s].y; }
            lax[t] = sx; lay[t] = sy;
        }

        // two independent dynamics chains (ILP)
        float vx = 0.0f, sxx = 0.0f, mx = 1e30f, cfx = 0.0f;
        float vy = 0.0f, syy = 0.0f, my = 1e30f, cfy = 0.0f;
        for (int oi = 0; oi < Tsz; ++oi) {
            float cx = 0.0f, cy = 0.0f;
#pragma unroll
            for (int t = 0; t < Tsz; ++t) {
                vx = vx * 0.2f * (1.0f - sxx) + lax[t];
                vy = vy * 0.2f * (1.0f - syy) + lay[t];
                mx = fminf(mx, fabsf(vx - 0.5f));
                my = fminf(my, fabsf(vy - 0.5f));
                sxx = (vx > 0.5f) ? 1.0f : 0.0f;
                syy = (vy > 0.5f) ? 1.0f : 0.0f;
                cx += sxx; cy += syy;
            }
            cfx = cx; cfy = cy;
        }
        float2 o2; o2.x = cfx; o2.y = cfy;
        *reinterpret_cast<float2*>(out + (size_t)b * Osz + o) = o2;
        if (mx < MARGIN) { int sl = atomicAdd(&cnt, 1); list[sl] = o; }
        if (my < MARGIN) { int sl = atomicAdd(&cnt, 1); list[sl] = o + 1; }
    }
    __syncthreads();

    const int n = cnt;
    if (n == 0) return;

    // stage x[b] (12 x 1024) into LDS, coalesced
    const float* xb = x + (size_t)b * Tsz * Dsz;
    for (int i = tid; i < Tsz * Dsz / 4; i += 256)
        reinterpret_cast<float4*>(xs)[i] = reinterpret_cast<const float4*>(xb)[i];
    __syncthreads();

    // one wave per flagged pair: exact fp64 dot over k, then fp64 dynamics on lane 0
    const int wv = tid >> 6;
    const int l  = tid & 63;
    for (int fi = wv; fi < n; fi += 4) {
        const int oo = list[fi];
        const float* wr = Wm + (size_t)oo * Dsz + l * 16;
        double dot[Tsz];
#pragma unroll
        for (int t = 0; t < Tsz; ++t) dot[t] = 0.0;
#pragma unroll
        for (int c4 = 0; c4 < 4; ++c4) {
            float4 w4 = *reinterpret_cast<const float4*>(wr + c4 * 4);
            const double w0 = (double)w4.x, w1 = (double)w4.y,
                         w2 = (double)w4.z, w3 = (double)w4.w;
#pragma unroll
            for (int t = 0; t < Tsz; ++t) {
                float4 x4 = *reinterpret_cast<const float4*>(xs + t * Dsz + l * 16 + c4 * 4);
                double d = dot[t];
                d = fma((double)x4.x, w0, d);
                d = fma((double)x4.y, w1, d);
                d = fma((double)x4.z, w2, d);
                dot[t] = fma((double)x4.w, w3, d);
            }
        }
#pragma unroll
        for (int off = 32; off; off >>= 1)
#pragma unroll
            for (int t = 0; t < Tsz; ++t)
                dot[t] += __shfl_down(dot[t], off);
        if (l == 0) {
            const double bvd = (double)bias[oo];
            double v = 0.0, s = 0.0, c = 0.0;
            for (int oi = 0; oi < Tsz; ++oi) {
                c = 0.0;
#pragma unroll
                for (int t = 0; t < Tsz; ++t) {
                    v = v * 0.2 * (1.0 - s) + (dot[t] + bvd);
                    s = (v > 0.5) ? 1.0 : 0.0;
                    c += s;
                }
            }
            out[(size_t)b * Osz + oo] = (float)c;
        }
    }
}

// ---------------- Fallback: proven round-1 fused fp64 kernel (ws too small) ----------------
#define F_AST 100
#define F_WST 68
#define F_BUFST 65
#define F_ABYTES (32 * F_AST * 4)

__global__ __launch_bounds__(192) void snn_fused_fb(
    const float* __restrict__ x, const float* __restrict__ Wm,
    const float* __restrict__ bias, float* __restrict__ out)
{
    __shared__ __align__(16) char smem[96 * F_BUFST * 8];
    float*  AsT = reinterpret_cast<float*>(smem);
    float*  WsT = reinterpret_cast<float*>(smem + F_ABYTES);
    double* buf = reinterpret_cast<double*>(smem);

    const int tid = threadIdx.x;
    const int ty  = tid >> 4;
    const int tx  = tid & 15;
    const int n0 = blockIdx.x * 64;
    const int b0 = blockIdx.y * 8;
    const int r0 = b0 * Tsz;

    double acc[8][4];
#pragma unroll
    for (int i = 0; i < 8; ++i)
#pragma unroll
        for (int j = 0; j < 4; ++j) acc[i][j] = 0.0;

    const float* Abase = x  + (size_t)r0 * Dsz;
    const float* Wbase = Wm + (size_t)n0 * Dsz;

    for (int k0 = 0; k0 < Dsz; k0 += 32) {
        __syncthreads();
#pragma unroll
        for (int it = 0; it < 4; ++it) {
            int idx = tid + 192 * it;
            int row = idx >> 3, c4 = idx & 7;
            float4 v = *reinterpret_cast<const float4*>(Abase + (size_t)row * Dsz + k0 + c4 * 4);
            int kb = c4 * 4;
            AsT[(kb + 0) * F_AST + row] = v.x;
            AsT[(kb + 1) * F_AST + row] = v.y;
            AsT[(kb + 2) * F_AST + row] = v.z;
            AsT[(kb + 3) * F_AST + row] = v.w;
        }
#pragma unroll
        for (int it = 0; it < 3; ++it) {
            int idx = tid + 192 * it;
            if (idx < 512) {
                int row = idx >> 3, c4 = idx & 7;
                float4 v = *reinterpret_cast<const float4*>(Wbase + (size_t)row * Dsz + k0 + c4 * 4);
                int kb = c4 * 4;
                WsT[(kb + 0) * F_WST + row] = v.x;
                WsT[(kb + 1) * F_WST + row] = v.y;
                WsT[(kb + 2) * F_WST + row] = v.z;
                WsT[(kb + 3) * F_WST + row] = v.w;
            }
        }
        __syncthreads();
#pragma unroll 4
        for (int kk = 0; kk < 32; ++kk) {
            const float* ar = &AsT[kk * F_AST + ty * 8];
            float4 a0 = *reinterpret_cast<const float4*>(ar);
            float4 a1 = *reinterpret_cast<const float4*>(ar + 4);
            float4 w0 = *reinterpret_cast<const float4*>(&WsT[kk * F_WST + tx * 4]);
            double ad[8] = {(double)a0.x, (double)a0.y, (double)a0.z, (double)a0.w,
                            (double)a1.x, (double)a1.y, (double)a1.z, (double)a1.w};
            double wd[4] = {(double)w0.x, (double)w0.y, (double)w0.z, (double)w0.w};
#pragma unroll
            for (int i = 0; i < 8; ++i)
#pragma unroll
                for (int j = 0; j < 4; ++j)
                    acc[i][j] = fma(ad[i], wd[j], acc[i][j]);
        }
    }
    __syncthreads();
#pragma unroll
    for (int i = 0; i < 8; ++i)
#pragma unroll
        for (int j = 0; j < 4; ++j)
            buf[(ty * 8 + i) * F_BUFST + (tx * 4 + j)] = acc[i][j];
    __syncthreads();

    for (int idx = tid; idx < 512; idx += 192) {
        int bl = idx >> 6, ol = idx & 63;
        double bv = (double)bias[n0 + ol];
        double la[Tsz];
#pragma unroll
        for (int t = 0; t < Tsz; ++t)
            la[t] = buf[(bl * Tsz + t) * F_BUFST + ol] + bv;
        double v = 0.0, s = 0.0;
        float cnt = 0.0f;
        for (int oi = 0; oi < Tsz; ++oi) {
            double c = 0.0;
#pragma unroll
            for (int t = 0; t < Tsz; ++t) {
                v = v * 0.2 * (1.0 - s) + la[t];
                s = (v > 0.5) ? 1.0 : 0.0;
                c += s;
            }
            cnt = (float)c;
        }
        out[(size_t)(b0 + bl) * Osz + (n0 + ol)] = cnt;
    }
}

extern "C" void kernel_launch(void* const* d_in, const int* in_sizes, int n_in,
                              void* d_out, int out_size, void* d_ws, size_t ws_size,
                              hipStream_t stream) {
    const float* x    = (const float*)d_in[0];   // (512,12,1024) fp32
    const float* Wm   = (const float*)d_in[1];   // (512,1024) fp32
    const float* bias = (const float*)d_in[2];   // (512) fp32
    float* out = (float*)d_out;                  // (512,512) fp32

    if (ws_size >= 2 * LIN_BYTES) {
        float* lin = (float*)d_ws;
        dim3 g1(Mrows / BM, Osz / BN, 2);        // 64 x 4 x 2 = 512 blocks = 2/CU exact
        hipLaunchKernelGGL(gemm_tile, g1, dim3(NTH1), 0, stream, x, Wm, lin, 16);
        hipLaunchKernelGGL((dyn_fix<2>), dim3(Bsz), dim3(256), 0, stream,
                           lin, x, Wm, bias, out);
    } else if (ws_size >= LIN_BYTES) {
        float* lin = (float*)d_ws;
        dim3 g1(Mrows / BM, Osz / BN, 1);        // 256 blocks
        hipLaunchKernelGGL(gemm_tile, g1, dim3(NTH1), 0, stream, x, Wm, lin, 32);
        hipLaunchKernelGGL((dyn_fix<1>), dim3(Bsz), dim3(256), 0, stream,
                           lin, x, Wm, bias, out);
    } else {
        dim3 grid(Osz / 64, Bsz / 8);            // (8, 64)
        hipLaunchKernelGGL(snn_fused_fb, grid, dim3(192), 0, stream, x, Wm, bias, out);
    }
}